// Round 2
// baseline (494.703 us; speedup 1.0000x reference)
//
#include <hip/hip_runtime.h>

// Decoder_33208687133135 — fused Koopman decoder, MI355X (gfx950).
// Only the diagonal of s,t survives -> layer4 is a per-row dot with one W4
// column. ~292 GFLOP, f16 MFMA (absmax 0.0625 vs thr 0.2425).
//
// R5 post-mortem: 375 us main. Spill fixed exactly as predicted (WRITE 82MB
// ->0.5MB) but time WORSE than R4's 350: R4 had 2 blocks/CU cross-block
// phase overlap; R5's single 1024-thr block is barrier-lockstep (MfmaUtil 36
// + VALUBusy 44, never overlapped). R6: exploit row-independence of the MLP
// (H[m,:] depends only on z[m,:]): 4096 blocks x 512 thr, block = 32 rows of
// one batch elem. Wave tile 32x64 -> acc[2][4]=32, bb dbuf 64, a[2] 16 ->
// ~120 regs < 128 class (R4 needed 144 -> spilled). LDS 36.75KB -> 2
// blocks/CU (VGPR-limited), independent blocks fill each other's
// barrier/tanh gaps. tanh moved BEFORE the read-barrier (into regs).
// Price: B weight L2 traffic 2x (4.67->9.3GB) — next ceiling to attack.

typedef _Float16 f16;
typedef _Float16 f16x8 __attribute__((ext_vector_type(8)));
typedef float f32x4 __attribute__((ext_vector_type(4)));

#define WPACK_PER_NET 589824
#define OFF_W1 0
#define OFF_W2 32768
#define OFF_W3 294912
#define OFF_W4T 557056
#define WPACK_BYTES (2u * WPACK_PER_NET * sizeof(f16))  // 2.36 MB

// ---------------- prologue: pack weights fp32 -> f16 blocked -------------
// B-fragment (16x16x32): B[k][n] held as n=lane&15, k=8*(lane>>4)+j.
// Blocked flat index: ((kk*32 + nt)*64 + (n&15) + 16*((k>>3)&3))*8 + (k&7).
// 8 consecutive flat indices per thread (j=0..7), one f16x8 store.
__global__ void pack_weights(const float* __restrict__ sW1, const float* __restrict__ sW2,
                             const float* __restrict__ sW3, const float* __restrict__ sW4,
                             const float* __restrict__ tW1, const float* __restrict__ tW2,
                             const float* __restrict__ tW3, const float* __restrict__ tW4,
                             f16* __restrict__ dst) {
  int idx8 = (blockIdx.x * 256 + threadIdx.x) * 8;
  if (idx8 >= 2 * WPACK_PER_NET) return;
  int net = idx8 >= WPACK_PER_NET;
  int f = idx8 - net * WPACK_PER_NET;
  const float* W1 = net ? tW1 : sW1;
  const float* W2 = net ? tW2 : sW2;
  const float* W3 = net ? tW3 : sW3;
  const float* W4 = net ? tW4 : sW4;
  f16x8 o;
  if (f < OFF_W2) {               // W1: (64,512)
    int lane = (f >> 3) & 63, nt = (f >> 9) & 31, kk = f >> 14;
    int r0 = kk * 32 + (lane >> 4) * 8, c = nt * 16 + (lane & 15);
#pragma unroll
    for (int j = 0; j < 8; j++) o[j] = (f16)W1[(r0 + j) * 512 + c];
  } else if (f < OFF_W3) {        // W2: (512,512)
    int f2 = f - OFF_W2;
    int lane = (f2 >> 3) & 63, nt = (f2 >> 9) & 31, kk = f2 >> 14;
    int r0 = kk * 32 + (lane >> 4) * 8, c = nt * 16 + (lane & 15);
#pragma unroll
    for (int j = 0; j < 8; j++) o[j] = (f16)W2[(r0 + j) * 512 + c];
  } else if (f < OFF_W4T) {       // W3: (512,512)
    int f3 = f - OFF_W3;
    int lane = (f3 >> 3) & 63, nt = (f3 >> 9) & 31, kk = f3 >> 14;
    int r0 = kk * 32 + (lane >> 4) * 8, c = nt * 16 + (lane & 15);
#pragma unroll
    for (int j = 0; j < 8; j++) o[j] = (f16)W3[(r0 + j) * 512 + c];
  } else {                        // W4: (512,64) -> W4T[i][k], k consecutive
    int f4 = f - OFF_W4T;
    int i = f4 >> 9, k0 = f4 & 511;
#pragma unroll
    for (int j = 0; j < 8; j++) o[j] = (f16)W4[(k0 + j) * 64 + i];
  }
  *(f16x8*)(dst + net * WPACK_PER_NET + f) = o;
}

// A-fragment order index for a 32-row A matrix, element (m,k), m in [0,32):
// chunk = (k>>5)*2 + (m>>4); lane = (m&15) + 16*((k>>3)&3); j = k&7.
__device__ __forceinline__ int aidx32(int m, int k) {
  return (((k >> 5) * 2 + (m >> 4)) * 64 + (m & 15) + ((k >> 3) & 3) * 16) * 8 + (k & 7);
}

// tanh(x) = 1 - 2/(exp(2x)+1). 6 VALU inst (2 trans-pipe). Saturates
// correctly at +/-inf, no clamp needed.
__device__ __forceinline__ float fast_tanh(float x) {
  float e = __expf(x + x);
  return fmaf(-2.0f, __builtin_amdgcn_rcpf(e + 1.0f), 1.0f);
}

// Load the wave's 4 B-fragments (64 cols) for k-slice kk.
// PACKED: lane-contiguous 16B loads from the frag-blocked f16 buffer (L2).
// DIRECT: coalesced fp32 gather from row-major W, convert in regs.
// Global col-tile index = wave*4 + nt (wave owns cols [64w, 64w+64)).
template <bool PACKED>
__device__ __forceinline__ void load_b(const f16* __restrict__ Wblk,
                                       const float* __restrict__ Wraw,
                                       int kk, int wave, int lane, f16x8* bdst) {
  if (PACKED) {
#pragma unroll
    for (int nt = 0; nt < 4; nt++)
      bdst[nt] = *(const f16x8*)(Wblk + kk * 16384 + ((wave * 4 + nt) * 64 + lane) * 8);
  } else {
    int n0 = wave * 64 + (lane & 15);
    int kb = kk * 32 + (lane >> 4) * 8;
#pragma unroll
    for (int nt = 0; nt < 4; nt++) {
      f16x8 v;
#pragma unroll
      for (int j = 0; j < 8; j++) v[j] = (f16)Wraw[(kb + j) * 512 + n0 + nt * 16];
      bdst[nt] = v;
    }
  }
}

// One MLP layer: Hout(32x512) = tanh(Asrc(32xK) @ W(Kx512) + bias).
// 8 waves; wave w owns output cols [64w, 64w+64), all 32 rows (mt=0,1).
// Weights stream L2->VGPR, depth-1 alternating-buffer prefetch; no weight
// LDS, no intra-loop barriers. acc[2][4]=32 + bb dbuf 64 + a 16 ~= 120 regs
// in the 128 class (launch_bounds(512,4)): no spill, 2 blocks/CU.
template <int NS, bool PACKED>
__device__ __forceinline__ void mlp_layer(const f16* __restrict__ Wblk,
                                          const float* __restrict__ Wraw,
                                          const float* __restrict__ bias,
                                          const f16* Asrc, f16* Hout,
                                          int wave, int lane, int sbase) {
  f32x4 acc[2][4];
#pragma unroll
  for (int nt = 0; nt < 4; nt++) {
    float bv = bias[wave * 64 + nt * 16 + (lane & 15)];
#pragma unroll
    for (int mt = 0; mt < 2; mt++) acc[mt][nt] = f32x4{bv, bv, bv, bv};
  }

  f16x8 bb[2][4];
  load_b<PACKED>(Wblk, Wraw, 0, wave, lane, bb[0]);
#pragma unroll
  for (int kk = 0; kk < NS; kk++) {
    if (kk + 1 < NS) load_b<PACKED>(Wblk, Wraw, kk + 1, wave, lane, bb[(kk + 1) & 1]);
    const f16* ab = Asrc + kk * 1024 + lane * 8;  // + mt*512 per mt (imm)
    f16x8 a[2];
#pragma unroll
    for (int mt = 0; mt < 2; mt++) a[mt] = *(const f16x8*)(ab + mt * 512);
#pragma unroll
    for (int mt = 0; mt < 2; mt++)
#pragma unroll
      for (int nt = 0; nt < 4; nt++)
        acc[mt][nt] = __builtin_amdgcn_mfma_f32_16x16x32_f16(a[mt], bb[kk & 1][nt],
                                                             acc[mt][nt], 0, 0, 0);
  }

  // tanh BEFORE the read-barrier: pure register work — fast waves convert
  // while slow waves are still in their MFMA loop (a/bb are dead here, so
  // hreg overlays them; no extra pressure).
  f16 hreg[32];
#pragma unroll
  for (int mt = 0; mt < 2; mt++)
#pragma unroll
    for (int nt = 0; nt < 4; nt++)
#pragma unroll
      for (int r = 0; r < 4; r++)
        hreg[(mt * 4 + nt) * 4 + r] = (f16)fast_tanh(acc[mt][nt][r]);

  __syncthreads();  // all waves done reading Asrc (may alias Hout)

  // C/D layout (m89/m91): col = wave*64 + nt*16 + (lane&15),
  // row = mt*16 + (lane>>4)*4 + r. Target A-frag elem index decomposes as
  // sbase(lane) + const(mt,nt,r)  [algebra re-derived for M=32 blocks,
  // spot-checked vs aidx32 at (w,l,mt,nt,r)=(0,0,0,0,0),(0,17,1,1,2),
  // (3,60,1,2,3)]:
  //   sbase = wave*2048 + (lane>>4)*32 + ((lane&15)>>3)*128 + (lane&7)
  //   const = (nt>>1)*1024 + (nt&1)*256 + mt*512 + r*8
  // -> ds_write_b16 with immediate offsets, zero per-store address VALU.
  f16* hb = Hout + sbase;
#pragma unroll
  for (int mt = 0; mt < 2; mt++)
#pragma unroll
    for (int nt = 0; nt < 4; nt++)
#pragma unroll
      for (int r = 0; r < 4; r++)
        hb[(nt >> 1) * 1024 + (nt & 1) * 256 + mt * 512 + r * 8] =
            hreg[(mt * 4 + nt) * 4 + r];
  __syncthreads();
}

template <bool PACKED>
__global__ __launch_bounds__(512, 4) void decoder_main(
    const float* __restrict__ x, const float* __restrict__ koop,
    const f16* __restrict__ wpack,
    const float* __restrict__ sW1, const float* __restrict__ sW2,
    const float* __restrict__ sW3, const float* __restrict__ sW4,
    const float* __restrict__ tW1, const float* __restrict__ tW2,
    const float* __restrict__ tW3, const float* __restrict__ tW4,
    const float* __restrict__ sb1, const float* __restrict__ sb2,
    const float* __restrict__ sb3, const float* __restrict__ sb4,
    const float* __restrict__ tb1, const float* __restrict__ tb2,
    const float* __restrict__ tb3, const float* __restrict__ tb4,
    float* __restrict__ out) {
  __shared__ __align__(16) f16 ZA[2048];   // z half-tile, A-frag order (4 KB)
  __shared__ __align__(16) f16 HA[16384];  // activations 32x512 (32 KB)
  __shared__ float redBuf[2][32];          // ds, dt
  // total 36.75 KB; 512 thr, ~120 regs -> 2 blocks/CU (16 waves, 4/SIMD)

  const int bid = blockIdx.x;
  const int b = bid >> 1, rr = bid & 1;    // batch elem, row-half
  const int t = threadIdx.x;
  const int wave = t >> 6, lane = t & 63;
  const int sbase =
      wave * 2048 + (lane >> 4) * 32 + ((lane & 15) >> 3) * 128 + (lane & 7);

  // Stage z-half: rows m=0..31 are d = rr*32+m; z[m][l] = koop[b][l][rr*32+m].
  const float* kb = koop + b * 4096 + rr * 32;
#pragma unroll
  for (int i = 0; i < 4; i++) {
    int flat = t + 512 * i;                 // 2048 elems, 32-float runs
    int l = flat >> 5, dl = flat & 31;
    ZA[aidx32(dl, l)] = (f16)kb[l * 64 + dl];
  }
  __syncthreads();

  for (int net = 0; net < 2; net++) {
    const f16* wb = PACKED ? (wpack + net * WPACK_PER_NET) : (const f16*)0;
    const float* W1 = net ? tW1 : sW1;
    const float* W2 = net ? tW2 : sW2;
    const float* W3 = net ? tW3 : sW3;
    const float* W4 = net ? tW4 : sW4;
    const float* b1 = net ? tb1 : sb1;
    const float* b2 = net ? tb2 : sb2;
    const float* b3 = net ? tb3 : sb3;
    const float* b4 = net ? tb4 : sb4;
    mlp_layer<2, PACKED>(PACKED ? wb + OFF_W1 : 0, W1, b1, ZA, HA, wave, lane, sbase);
    mlp_layer<16, PACKED>(PACKED ? wb + OFF_W2 : 0, W2, b2, HA, HA, wave, lane, sbase);
    mlp_layer<16, PACKED>(PACKED ? wb + OFF_W3 : 0, W3, b3, HA, HA, wave, lane, sbase);

    // Diagonal epilogue: ds[ig] = H3[i,:] . W4[:,ig] + b4[ig], ig = rr*32+i.
    // 16 threads per row (all 512 threads active).
    int i = t >> 4, sub = t & 15;
    int ig = rr * 32 + i;
    float p = 0.f;
#pragma unroll
    for (int q = 0; q < 4; q++) {
      int k0 = sub * 32 + q * 8;
      f16x8 hv = *(const f16x8*)&HA[aidx32(i, k0)];
      if (PACKED) {
        f16x8 wv = *(const f16x8*)&wb[OFF_W4T + ig * 512 + k0];
#pragma unroll
        for (int j = 0; j < 8; j++) p += (float)hv[j] * (float)wv[j];
      } else {
#pragma unroll
        for (int j = 0; j < 8; j++) p += (float)hv[j] * W4[(k0 + j) * 64 + ig];
      }
    }
    p += __shfl_down(p, 8, 16);
    p += __shfl_down(p, 4, 16);
    p += __shfl_down(p, 2, 16);
    p += __shfl_down(p, 1, 16);
    if (sub == 0) redBuf[net][i] = p + b4[ig];
    __syncthreads();
  }

  if (t < 32) {
    int ig = rr * 32 + t;
    out[b * 64 + ig] = (x[b * 64 + ig] - redBuf[1][t]) * __expf(-redBuf[0][t]);
  }
}

extern "C" void kernel_launch(void* const* d_in, const int* in_sizes, int n_in,
                              void* d_out, int out_size, void* d_ws, size_t ws_size,
                              hipStream_t stream) {
  const float* x    = (const float*)d_in[0];
  const float* koop = (const float*)d_in[1];
  const float* sW1 = (const float*)d_in[2];  const float* sb1 = (const float*)d_in[3];
  const float* sW2 = (const float*)d_in[4];  const float* sb2 = (const float*)d_in[5];
  const float* sW3 = (const float*)d_in[6];  const float* sb3 = (const float*)d_in[7];
  const float* sW4 = (const float*)d_in[8];  const float* sb4 = (const float*)d_in[9];
  const float* tW1 = (const float*)d_in[10]; const float* tb1 = (const float*)d_in[11];
  const float* tW2 = (const float*)d_in[12]; const float* tb2 = (const float*)d_in[13];
  const float* tW3 = (const float*)d_in[14]; const float* tb3 = (const float*)d_in[15];
  const float* tW4 = (const float*)d_in[16]; const float* tb4 = (const float*)d_in[17];
  float* out = (float*)d_out;

  // Launch-invariant branch (ws_size constant across calls) -> graph-safe.
  // NEVER write past ws_size (R1: OOB pack corrupted harness allocations).
  if (ws_size >= (size_t)WPACK_BYTES) {
    f16* wpack = (f16*)d_ws;
    pack_weights<<<576, 256, 0, stream>>>(sW1, sW2, sW3, sW4, tW1, tW2, tW3, tW4, wpack);
    decoder_main<true><<<4096, 512, 0, stream>>>(
        x, koop, wpack, sW1, sW2, sW3, sW4, tW1, tW2, tW3, tW4,
        sb1, sb2, sb3, sb4, tb1, tb2, tb3, tb4, out);
  } else {
    decoder_main<false><<<4096, 512, 0, stream>>>(
        x, koop, (const f16*)0, sW1, sW2, sW3, sW4, tW1, tW2, tW3, tW4,
        sb1, sb2, sb3, sb4, tb1, tb2, tb3, tb4, out);
  }
}

// Round 3
// 476.153 us; speedup vs baseline: 1.0390x; 1.0390x over previous
//
#include <hip/hip_runtime.h>

// Decoder_33208687133135 — fused Koopman decoder, MI355X (gfx950).
// Only the diagonal of s,t survives -> layer4 is a per-row dot with one W4
// column. ~292 GFLOP, f16 MFMA (absmax 0.0625 vs thr 0.2425).
//
// R6 post-mortem: 416 us. Clean (no spill) + 2 blk/CU overlap, but M_blk=32
// DOUBLED the L2 weight stream (9.4GB -> 22.6 TB/s sustained, 65% of L2
// ceiling) and HALVED B-frag reuse (2 MFMA/frag): latency-bound on B.
// Ranking R4(350,overlap+reuse4+spill) < R5(375,lockstep) < R6(416).
// R7: R4's structure minus its spill. 512 thr, M_blk=64, but N=512 done in
// TWO sequential 256-col passes -> acc[4][2]=32 regs (not 64), reuse 4,
// traffic 4.7GB, 72.5KB LDS -> 2 blocks/CU, ~115 regs peak (no spill).
// B-prefetch chains across pass/layer boundaries (pb survives barriers),
// per-mt single a-frag load keeps liveness down.

typedef _Float16 f16;
typedef _Float16 f16x8 __attribute__((ext_vector_type(8)));
typedef float f32x4 __attribute__((ext_vector_type(4)));

#define WPACK_PER_NET 589824
#define OFF_W1 0
#define OFF_W2 32768
#define OFF_W3 294912
#define OFF_W4T 557056
#define WPACK_BYTES (2u * WPACK_PER_NET * sizeof(f16))  // 2.36 MB

// ---------------- prologue: pack weights fp32 -> f16 blocked -------------
// B-fragment (16x16x32): B[k][n] held as n=lane&15, k=8*(lane>>4)+j.
// Blocked flat index: ((kk*32 + nt)*64 + (n&15) + 16*((k>>3)&3))*8 + (k&7).
// 8 consecutive flat indices per thread (j=0..7), one f16x8 store.
__global__ void pack_weights(const float* __restrict__ sW1, const float* __restrict__ sW2,
                             const float* __restrict__ sW3, const float* __restrict__ sW4,
                             const float* __restrict__ tW1, const float* __restrict__ tW2,
                             const float* __restrict__ tW3, const float* __restrict__ tW4,
                             f16* __restrict__ dst) {
  int idx8 = (blockIdx.x * 256 + threadIdx.x) * 8;
  if (idx8 >= 2 * WPACK_PER_NET) return;
  int net = idx8 >= WPACK_PER_NET;
  int f = idx8 - net * WPACK_PER_NET;
  const float* W1 = net ? tW1 : sW1;
  const float* W2 = net ? tW2 : sW2;
  const float* W3 = net ? tW3 : sW3;
  const float* W4 = net ? tW4 : sW4;
  f16x8 o;
  if (f < OFF_W2) {               // W1: (64,512)
    int lane = (f >> 3) & 63, nt = (f >> 9) & 31, kk = f >> 14;
    int r0 = kk * 32 + (lane >> 4) * 8, c = nt * 16 + (lane & 15);
#pragma unroll
    for (int j = 0; j < 8; j++) o[j] = (f16)W1[(r0 + j) * 512 + c];
  } else if (f < OFF_W3) {        // W2: (512,512)
    int f2 = f - OFF_W2;
    int lane = (f2 >> 3) & 63, nt = (f2 >> 9) & 31, kk = f2 >> 14;
    int r0 = kk * 32 + (lane >> 4) * 8, c = nt * 16 + (lane & 15);
#pragma unroll
    for (int j = 0; j < 8; j++) o[j] = (f16)W2[(r0 + j) * 512 + c];
  } else if (f < OFF_W4T) {       // W3: (512,512)
    int f3 = f - OFF_W3;
    int lane = (f3 >> 3) & 63, nt = (f3 >> 9) & 31, kk = f3 >> 14;
    int r0 = kk * 32 + (lane >> 4) * 8, c = nt * 16 + (lane & 15);
#pragma unroll
    for (int j = 0; j < 8; j++) o[j] = (f16)W3[(r0 + j) * 512 + c];
  } else {                        // W4: (512,64) -> W4T[i][k], k consecutive
    int f4 = f - OFF_W4T;
    int i = f4 >> 9, k0 = f4 & 511;
#pragma unroll
    for (int j = 0; j < 8; j++) o[j] = (f16)W4[(k0 + j) * 64 + i];
  }
  *(f16x8*)(dst + net * WPACK_PER_NET + f) = o;
}

// A-fragment order index for a 64-row A matrix, element (m,k):
// chunk = (k>>5)*4 + (m>>4); lane = (m&15) + 16*((k>>3)&3); j = k&7.
__device__ __forceinline__ int aidx(int m, int k) {
  return (((k >> 5) * 4 + (m >> 4)) * 64 + (m & 15) + ((k >> 3) & 3) * 16) * 8 + (k & 7);
}

// tanh(x) = 1 - 2/(exp(2x)+1). 6 VALU inst (2 trans-pipe). Saturates
// correctly at +/-inf, no clamp needed.
__device__ __forceinline__ float fast_tanh(float x) {
  float e = __expf(x + x);
  return fmaf(-2.0f, __builtin_amdgcn_rcpf(e + 1.0f), 1.0f);
}

// Load the wave's 2 B-fragments (32 cols) for k-slice kk, col-pass `pass`.
// Wave w owns cols [pass*256 + 32w, +32). Col-tile index ct = pass*16+2w+nt.
// PACKED: lane-contiguous 16B loads from the frag-blocked f16 buffer (L2).
// DIRECT: coalesced fp32 gather from row-major W, convert in regs.
template <bool PACKED>
__device__ __forceinline__ void load_b(const f16* __restrict__ Wblk,
                                       const float* __restrict__ Wraw,
                                       int kk, int pass, int wave, int lane,
                                       f16x8* bdst) {
  if (PACKED) {
#pragma unroll
    for (int nt = 0; nt < 2; nt++)
      bdst[nt] = *(const f16x8*)(Wblk + kk * 16384 +
                                 ((pass * 16 + wave * 2 + nt) * 64 + lane) * 8);
  } else {
    int n0 = pass * 256 + wave * 32 + (lane & 15);
    int kb = kk * 32 + (lane >> 4) * 8;
#pragma unroll
    for (int nt = 0; nt < 2; nt++) {
      f16x8 v;
#pragma unroll
      for (int j = 0; j < 8; j++) v[j] = (f16)Wraw[(kb + j) * 512 + n0 + nt * 16];
      bdst[nt] = v;
    }
  }
}

// One MLP layer: Hout(64x512) = tanh(Asrc(64xK) @ W(Kx512) + bias).
// 8 waves; wave w covers cols [32w,32w+32) in pass 0 and [256+32w,+32) in
// pass 1 (sequential passes -> acc[4][2]=32 regs, B-frag reuse 4).
// Weights stream L2->VGPR, depth-1 alternating-buffer prefetch inside the
// kk-loop; pb carries the NEXT (pass/layer) k-slice-0 fragments across the
// tanh + barriers so no segment starts cold on L2 latency.
template <int NS, bool PACKED>
__device__ __forceinline__ void mlp_layer(const f16* __restrict__ Wblk,
                                          const float* __restrict__ Wraw,
                                          const float* __restrict__ bias,
                                          const f16* Asrc, f16* Hout,
                                          int wave, int lane, int sbase,
                                          f16x8* pb,
                                          const f16* __restrict__ WblkN,
                                          const float* __restrict__ WrawN,
                                          bool hasNext) {
  f16 hreg[2][32];
#pragma unroll
  for (int pass = 0; pass < 2; pass++) {
    f32x4 acc[4][2];
#pragma unroll
    for (int nt = 0; nt < 2; nt++) {
      float bv = bias[pass * 256 + wave * 32 + nt * 16 + (lane & 15)];
#pragma unroll
      for (int mt = 0; mt < 4; mt++) acc[mt][nt] = f32x4{bv, bv, bv, bv};
    }
    f16x8 bb[2][2];
    bb[0][0] = pb[0];
    bb[0][1] = pb[1];
#pragma unroll
    for (int kk = 0; kk < NS; kk++) {
      if (kk + 1 < NS) {
        load_b<PACKED>(Wblk, Wraw, kk + 1, pass, wave, lane, bb[(kk + 1) & 1]);
      } else if (pass == 0) {
        load_b<PACKED>(Wblk, Wraw, 0, 1, wave, lane, pb);       // this layer, pass B
      } else if (hasNext) {
        load_b<PACKED>(WblkN, WrawN, 0, 0, wave, lane, pb);     // next layer, pass A
      }
      const f16* ab = Asrc + kk * 2048 + lane * 8;
#pragma unroll
      for (int mt = 0; mt < 4; mt++) {
        f16x8 a = *(const f16x8*)(ab + mt * 512);  // single live a-frag (8 regs)
#pragma unroll
        for (int nt = 0; nt < 2; nt++)
          acc[mt][nt] = __builtin_amdgcn_mfma_f32_16x16x32_f16(a, bb[kk & 1][nt],
                                                               acc[mt][nt], 0, 0, 0);
      }
    }
    // tanh into regs before the barrier: fast waves convert while slow waves
    // (and the co-resident block) still run their MFMA loops.
#pragma unroll
    for (int mt = 0; mt < 4; mt++)
#pragma unroll
      for (int nt = 0; nt < 2; nt++)
#pragma unroll
        for (int r = 0; r < 4; r++)
          hreg[pass][(mt * 2 + nt) * 4 + r] = (f16)fast_tanh(acc[mt][nt][r]);
  }
  __syncthreads();  // all waves done reading Asrc (Hout may alias Asrc)

  // C/D layout (m89/m91): col = pass*256 + wave*32 + nt*16 + (lane&15),
  // row = mt*16 + (lane>>4)*4 + r. Target A-frag index = sbase(lane,wave)
  // + const(pass,mt,nt,r)  [algebra verified vs aidx():
  //   aidx(m,n) = (w+8*pass)*2048 + mt*512 + 32(lane>>4)
  //               + 128((lane&15)>>3) + (lane&7) + nt*256 + r*8]
  //   sbase = wave*2048 + (lane>>4)*32 + ((lane&15)>>3)*128 + (lane&7)
  //   const = pass*16384 + mt*512 + nt*256 + r*8
  // -> ds_write_b16 with immediate offsets, zero per-store address VALU.
  f16* hb = Hout + sbase;
#pragma unroll
  for (int pass = 0; pass < 2; pass++)
#pragma unroll
    for (int mt = 0; mt < 4; mt++)
#pragma unroll
      for (int nt = 0; nt < 2; nt++)
#pragma unroll
        for (int r = 0; r < 4; r++)
          hb[pass * 16384 + mt * 512 + nt * 256 + r * 8] =
              hreg[pass][(mt * 2 + nt) * 4 + r];
  __syncthreads();
}

template <bool PACKED>
__global__ __launch_bounds__(512, 4) void decoder_main(
    const float* __restrict__ x, const float* __restrict__ koop,
    const f16* __restrict__ wpack,
    const float* __restrict__ sW1, const float* __restrict__ sW2,
    const float* __restrict__ sW3, const float* __restrict__ sW4,
    const float* __restrict__ tW1, const float* __restrict__ tW2,
    const float* __restrict__ tW3, const float* __restrict__ tW4,
    const float* __restrict__ sb1, const float* __restrict__ sb2,
    const float* __restrict__ sb3, const float* __restrict__ sb4,
    const float* __restrict__ tb1, const float* __restrict__ tb2,
    const float* __restrict__ tb3, const float* __restrict__ tb4,
    float* __restrict__ out) {
  __shared__ __align__(16) f16 ZA[4096];   // z tile, A-frag order (8 KB)
  __shared__ __align__(16) f16 HA[32768];  // activations 64x512 (64 KB)
  __shared__ float redBuf[2][64];          // ds, dt
  // total 72.5 KB; 512 thr, ~115 regs -> 2 blocks/CU (16 waves, 4/SIMD)

  const int b = blockIdx.x;
  const int t = threadIdx.x;
  const int wave = t >> 6, lane = t & 63;
  const int sbase =
      wave * 2048 + (lane >> 4) * 32 + ((lane & 15) >> 3) * 128 + (lane & 7);

  // Stage z = koopman[b]^T as f16 A-fragments: z[d][l] = koop[b][l][d].
  const float* kb = koop + b * 4096;
#pragma unroll
  for (int i = 0; i < 8; i++) {
    int flat = t + 512 * i;                 // coalesced fp32 read
    ZA[aidx(flat & 63, flat >> 6)] = (f16)kb[flat];
  }
  // Prefetch net-s L1 pass-0 k-slice-0 while ZA writes drain.
  f16x8 pb[2];
  load_b<PACKED>(PACKED ? wpack + OFF_W1 : 0, sW1, 0, 0, wave, lane, pb);
  __syncthreads();

  for (int net = 0; net < 2; net++) {
    const f16* wb = PACKED ? (wpack + net * WPACK_PER_NET) : (const f16*)0;
    const float* W1 = net ? tW1 : sW1;
    const float* W2 = net ? tW2 : sW2;
    const float* W3 = net ? tW3 : sW3;
    const float* W4 = net ? tW4 : sW4;
    const float* b1 = net ? tb1 : sb1;
    const float* b2 = net ? tb2 : sb2;
    const float* b3 = net ? tb3 : sb3;
    const float* b4 = net ? tb4 : sb4;
    mlp_layer<2, PACKED>(PACKED ? wb + OFF_W1 : 0, W1, b1, ZA, HA, wave, lane, sbase,
                         pb, PACKED ? wb + OFF_W2 : 0, W2, true);
    mlp_layer<16, PACKED>(PACKED ? wb + OFF_W2 : 0, W2, b2, HA, HA, wave, lane, sbase,
                          pb, PACKED ? wb + OFF_W3 : 0, W3, true);
    mlp_layer<16, PACKED>(PACKED ? wb + OFF_W3 : 0, W3, b3, HA, HA, wave, lane, sbase,
                          pb, (net == 0 && PACKED) ? wpack + WPACK_PER_NET + OFF_W1 : 0,
                          net == 0 ? tW1 : 0, net == 0);

    // Diagonal epilogue: ds[i] = H3[i,:] . W4[:,i] + b4[i].
    // 8 threads per row (all 512 threads active). pb (net-t L1) rides through.
    int i = t >> 3, sub = t & 7;
    float p = 0.f;
#pragma unroll
    for (int q = 0; q < 8; q++) {
      int k0 = sub * 64 + q * 8;
      f16x8 hv = *(const f16x8*)&HA[aidx(i, k0)];
      if (PACKED) {
        f16x8 wv = *(const f16x8*)&wb[OFF_W4T + i * 512 + k0];
#pragma unroll
        for (int j = 0; j < 8; j++) p += (float)hv[j] * (float)wv[j];
      } else {
#pragma unroll
        for (int j = 0; j < 8; j++) p += (float)hv[j] * W4[(k0 + j) * 64 + i];
      }
    }
    p += __shfl_down(p, 4, 8);
    p += __shfl_down(p, 2, 8);
    p += __shfl_down(p, 1, 8);
    if (sub == 0) redBuf[net][i] = p + b4[i];
    __syncthreads();
  }

  if (t < 64) {
    out[b * 64 + t] = (x[b * 64 + t] - redBuf[1][t]) * __expf(-redBuf[0][t]);
  }
}

extern "C" void kernel_launch(void* const* d_in, const int* in_sizes, int n_in,
                              void* d_out, int out_size, void* d_ws, size_t ws_size,
                              hipStream_t stream) {
  const float* x    = (const float*)d_in[0];
  const float* koop = (const float*)d_in[1];
  const float* sW1 = (const float*)d_in[2];  const float* sb1 = (const float*)d_in[3];
  const float* sW2 = (const float*)d_in[4];  const float* sb2 = (const float*)d_in[5];
  const float* sW3 = (const float*)d_in[6];  const float* sb3 = (const float*)d_in[7];
  const float* sW4 = (const float*)d_in[8];  const float* sb4 = (const float*)d_in[9];
  const float* tW1 = (const float*)d_in[10]; const float* tb1 = (const float*)d_in[11];
  const float* tW2 = (const float*)d_in[12]; const float* tb2 = (const float*)d_in[13];
  const float* tW3 = (const float*)d_in[14]; const float* tb3 = (const float*)d_in[15];
  const float* tW4 = (const float*)d_in[16]; const float* tb4 = (const float*)d_in[17];
  float* out = (float*)d_out;

  // Launch-invariant branch (ws_size constant across calls) -> graph-safe.
  // NEVER write past ws_size (R1: OOB pack corrupted harness allocations).
  if (ws_size >= (size_t)WPACK_BYTES) {
    f16* wpack = (f16*)d_ws;
    pack_weights<<<576, 256, 0, stream>>>(sW1, sW2, sW3, sW4, tW1, tW2, tW3, tW4, wpack);
    decoder_main<true><<<2048, 512, 0, stream>>>(
        x, koop, wpack, sW1, sW2, sW3, sW4, tW1, tW2, tW3, tW4,
        sb1, sb2, sb3, sb4, tb1, tb2, tb3, tb4, out);
  } else {
    decoder_main<false><<<2048, 512, 0, stream>>>(
        x, koop, (const f16*)0, sW1, sW2, sW3, sW4, tW1, tW2, tW3, tW4,
        sb1, sb2, sb3, sb4, tb1, tb2, tb3, tb4, out);
  }
}

// Round 4
// 455.459 us; speedup vs baseline: 1.0862x; 1.0454x over previous
//
#include <hip/hip_runtime.h>

// Decoder_33208687133135 — fused Koopman decoder, MI355X (gfx950).
// Only the diagonal of s,t survives -> layer4 is a per-row dot with one W4
// column. ~292 GFLOP, f16 MFMA (absmax 0.0625 vs thr 0.2425).
//
// R7 post-mortem: 417 us, VGPR 64(+spill), WRITE 340MB: two-pass hreg state
// blew the 128 class AND __syncthreads' vmcnt(0) drain killed the pb
// prefetch. Deeper truth from R4-R7 accounting: in the 16x16 structure each
// wave re-reads the full A tile (4 ds_read_b128 per 8 MFMA) -> LDS pipe
// 12.3k cyc vs MFMA 9.9k per block-layer: LDS-BOUND. No schedule fixes that.
// R8: 32x32x16 MFMA, wave tile 64x64. (1) A-reuse doubles: 2 ds_read per
// 4 MFMA -> LDS reads 6.1k < MFMA 8.3k; (2) 32x32 pipe is faster (2495 vs
// 2075 TF, floor 141->117us); (3) regs fit: acc 4xf32x16=64 + bb[2][2]=16
// + a 8 + misc ~110 < 128 @ 512thr -> 2 blocks/CU, clean. Overlap + reuse
// + no-spill for the first time. Scatter algebra re-derived for 32x32
// C/D (col=lane&31, row=(reg&3)+8*(reg>>2)+4*(lane>>5)), verified at 3
// concrete points.

typedef _Float16 f16;
typedef _Float16 f16x8 __attribute__((ext_vector_type(8)));
typedef float f32x16 __attribute__((ext_vector_type(16)));

#define WPACK_PER_NET 589824
#define OFF_W1 0
#define OFF_W2 32768
#define OFF_W3 294912
#define OFF_W4T 557056
#define WPACK_BYTES (2u * WPACK_PER_NET * sizeof(f16))  // 2.36 MB

// ---------------- prologue: pack weights fp32 -> f16 blocked -------------
// B-fragment (32x32x16): B[k][n] held as n=lane&31, k=8*(lane>>5)+j.
// Frag (ks,ctg) covers k in [16ks,16ks+16), n in [32ctg,32ctg+32).
// Blocked flat index: ((ks*16 + ctg)*64 + lane)*8 + j.
// 8 consecutive flat indices per thread (j=0..7), one f16x8 store.
__global__ void pack_weights(const float* __restrict__ sW1, const float* __restrict__ sW2,
                             const float* __restrict__ sW3, const float* __restrict__ sW4,
                             const float* __restrict__ tW1, const float* __restrict__ tW2,
                             const float* __restrict__ tW3, const float* __restrict__ tW4,
                             f16* __restrict__ dst) {
  int idx8 = (blockIdx.x * 256 + threadIdx.x) * 8;
  if (idx8 >= 2 * WPACK_PER_NET) return;
  int net = idx8 >= WPACK_PER_NET;
  int f = idx8 - net * WPACK_PER_NET;
  const float* W1 = net ? tW1 : sW1;
  const float* W2 = net ? tW2 : sW2;
  const float* W3 = net ? tW3 : sW3;
  const float* W4 = net ? tW4 : sW4;
  f16x8 o;
  if (f < OFF_W2) {               // W1: (64,512), ks<4
    int lane = (f >> 3) & 63, ctg = (f >> 9) & 15, ks = f >> 13;
    int r0 = ks * 16 + (lane >> 5) * 8, c = ctg * 32 + (lane & 31);
#pragma unroll
    for (int j = 0; j < 8; j++) o[j] = (f16)W1[(r0 + j) * 512 + c];
  } else if (f < OFF_W3) {        // W2: (512,512), ks<32
    int f2 = f - OFF_W2;
    int lane = (f2 >> 3) & 63, ctg = (f2 >> 9) & 15, ks = f2 >> 13;
    int r0 = ks * 16 + (lane >> 5) * 8, c = ctg * 32 + (lane & 31);
#pragma unroll
    for (int j = 0; j < 8; j++) o[j] = (f16)W2[(r0 + j) * 512 + c];
  } else if (f < OFF_W4T) {       // W3: (512,512)
    int f3 = f - OFF_W3;
    int lane = (f3 >> 3) & 63, ctg = (f3 >> 9) & 15, ks = f3 >> 13;
    int r0 = ks * 16 + (lane >> 5) * 8, c = ctg * 32 + (lane & 31);
#pragma unroll
    for (int j = 0; j < 8; j++) o[j] = (f16)W3[(r0 + j) * 512 + c];
  } else {                        // W4: (512,64) -> W4T[i][k], k consecutive
    int f4 = f - OFF_W4T;
    int i = f4 >> 9, k0 = f4 & 511;
#pragma unroll
    for (int j = 0; j < 8; j++) o[j] = (f16)W4[(k0 + j) * 64 + i];
  }
  *(f16x8*)(dst + net * WPACK_PER_NET + f) = o;
}

// A-fragment index for a 64-row matrix, element (m,k), 32x32x16 layout:
// A lane mapping: m = lane&31, k_in_slice = 8*(lane>>5) + j.
// chunk = (k>>4)*2 + (m>>5); within-chunk lane = (m&31) + 32*((k>>3)&1).
__device__ __forceinline__ int aidx(int m, int k) {
  return ((k >> 4) * 2 + (m >> 5)) * 512 + ((m & 31) + 32 * ((k >> 3) & 1)) * 8 + (k & 7);
}

// tanh(x) = 1 - 2/(exp(2x)+1). 6 VALU inst (2 trans-pipe). Saturates
// correctly at +/-inf, no clamp needed.
__device__ __forceinline__ float fast_tanh(float x) {
  float e = __expf(x + x);
  return fmaf(-2.0f, __builtin_amdgcn_rcpf(e + 1.0f), 1.0f);
}

// Load the wave's 2 B-fragments (64 cols = ctg 2w, 2w+1) for k-slice ks.
// PACKED: lane-contiguous 16B loads from the frag-blocked f16 buffer (L2).
// DIRECT: strided fp32 gather from row-major W, convert in regs.
template <bool PACKED>
__device__ __forceinline__ void load_b(const f16* __restrict__ Wblk,
                                       const float* __restrict__ Wraw,
                                       int ks, int wave, int lane, f16x8* bdst) {
  if (PACKED) {
#pragma unroll
    for (int ct = 0; ct < 2; ct++)
      bdst[ct] = *(const f16x8*)(Wblk + ((ks * 16 + wave * 2 + ct) * 64 + lane) * 8);
  } else {
    int r0 = ks * 16 + (lane >> 5) * 8;
    int n0 = wave * 64 + (lane & 31);
#pragma unroll
    for (int ct = 0; ct < 2; ct++) {
      f16x8 v;
#pragma unroll
      for (int j = 0; j < 8; j++) v[j] = (f16)Wraw[(r0 + j) * 512 + n0 + ct * 32];
      bdst[ct] = v;
    }
  }
}

// One MLP layer: Hout(64x512) = tanh(Asrc(64xK) @ W(Kx512) + bias).
// 8 waves; wave w owns output cols [64w,64w+64) via 2x2 32x32 MFMA tiles
// (mt = row-half, ct = col-tile). Weights stream L2->VGPR, depth-1
// alternating-buffer prefetch; A-frags from LDS (2 ds_read_b128 per ks
// feed 4 MFMAs -> half the LDS read traffic of the 16x16 structure).
template <int NS, bool PACKED, bool ALIASED>
__device__ __forceinline__ void mlp_layer(const f16* __restrict__ Wblk,
                                          const float* __restrict__ Wraw,
                                          const float* __restrict__ bias,
                                          const f16* Asrc, f16* Hout,
                                          int wave, int lane, int sbase) {
  f32x16 acc[2][2];
#pragma unroll
  for (int ct = 0; ct < 2; ct++) {
    float bv = bias[wave * 64 + ct * 32 + (lane & 31)];
#pragma unroll
    for (int mt = 0; mt < 2; mt++)
#pragma unroll
      for (int e = 0; e < 16; e++) acc[mt][ct][e] = bv;
  }

  f16x8 bb[2][2];
  load_b<PACKED>(Wblk, Wraw, 0, wave, lane, bb[0]);
#pragma unroll
  for (int ks = 0; ks < NS; ks++) {
    if (ks + 1 < NS) load_b<PACKED>(Wblk, Wraw, ks + 1, wave, lane, bb[(ks + 1) & 1]);
    const f16* ab = Asrc + ks * 1024 + lane * 8;  // chunk = ks*2 + mt
    f16x8 a0 = *(const f16x8*)ab;
    f16x8 a1 = *(const f16x8*)(ab + 512);
#pragma unroll
    for (int ct = 0; ct < 2; ct++) {
      acc[0][ct] = __builtin_amdgcn_mfma_f32_32x32x16_f16(a0, bb[ks & 1][ct],
                                                          acc[0][ct], 0, 0, 0);
      acc[1][ct] = __builtin_amdgcn_mfma_f32_32x32x16_f16(a1, bb[ks & 1][ct],
                                                          acc[1][ct], 0, 0, 0);
    }
  }
  if (ALIASED) __syncthreads();  // all waves done reading Asrc (== Hout)

  // C/D layout (m74/m101): col = wave*64 + ct*32 + (lane&31),
  // row = mt*32 + (reg&3) + 8*(reg>>2) + 4*(lane>>5).
  // Target A-frag index = sbase(lane,wave) + const(ct,mt,reg):
  //   sbase = wave*4096 + ((lane>>4)&1)*1024 + ((lane>>3)&1)*256
  //           + (lane>>5)*32 + (lane&7)
  //   const = ct*2048 + mt*512 + (reg>>2)*64 + (reg&3)*8
  // [verified at (w,l,mt,ct,reg) = (0,0,0,0,5)->72, (1,37,1,1,14)->6901,
  //  (0,27,0,0,0)->1283 against aidx()]
  // -> ds_write_b16 with immediate offsets, zero per-store address VALU.
  f16* hb = Hout + sbase;
#pragma unroll
  for (int mt = 0; mt < 2; mt++)
#pragma unroll
    for (int ct = 0; ct < 2; ct++)
#pragma unroll
      for (int reg = 0; reg < 16; reg++)
        hb[ct * 2048 + mt * 512 + (reg >> 2) * 64 + (reg & 3) * 8] =
            (f16)fast_tanh(acc[mt][ct][reg]);
  __syncthreads();
}

template <bool PACKED>
__global__ __launch_bounds__(512, 4) void decoder_main(
    const float* __restrict__ x, const float* __restrict__ koop,
    const f16* __restrict__ wpack,
    const float* __restrict__ sW1, const float* __restrict__ sW2,
    const float* __restrict__ sW3, const float* __restrict__ sW4,
    const float* __restrict__ tW1, const float* __restrict__ tW2,
    const float* __restrict__ tW3, const float* __restrict__ tW4,
    const float* __restrict__ sb1, const float* __restrict__ sb2,
    const float* __restrict__ sb3, const float* __restrict__ sb4,
    const float* __restrict__ tb1, const float* __restrict__ tb2,
    const float* __restrict__ tb3, const float* __restrict__ tb4,
    float* __restrict__ out) {
  __shared__ __align__(16) f16 ZA[4096];   // z tile, A-frag order (8 KB)
  __shared__ __align__(16) f16 HA[32768];  // activations 64x512 (64 KB)
  __shared__ float redBuf[2][64];          // ds, dt
  // total 72.5 KB; 512 thr, ~110 regs -> 2 blocks/CU (16 waves, 4/SIMD)

  const int b = blockIdx.x;
  const int t = threadIdx.x;
  const int wave = t >> 6, lane = t & 63;
  const int sbase = wave * 4096 + ((lane >> 4) & 1) * 1024 +
                    ((lane >> 3) & 1) * 256 + (lane >> 5) * 32 + (lane & 7);

  // Stage z = koopman[b]^T as f16 A-fragments: z[d][l] = koop[b][l][d].
  const float* kb = koop + b * 4096;
#pragma unroll
  for (int i = 0; i < 8; i++) {
    int flat = t + 512 * i;                 // coalesced fp32 read over d
    ZA[aidx(flat & 63, flat >> 6)] = (f16)kb[flat];
  }
  __syncthreads();

  for (int net = 0; net < 2; net++) {
    const f16* wb = PACKED ? (wpack + net * WPACK_PER_NET) : (const f16*)0;
    const float* W1 = net ? tW1 : sW1;
    const float* W2 = net ? tW2 : sW2;
    const float* W3 = net ? tW3 : sW3;
    const float* W4 = net ? tW4 : sW4;
    const float* b1 = net ? tb1 : sb1;
    const float* b2 = net ? tb2 : sb2;
    const float* b3 = net ? tb3 : sb3;
    const float* b4 = net ? tb4 : sb4;
    // L1 reads ZA (never overwritten) -> no pre-write barrier needed.
    mlp_layer<4, PACKED, false>(PACKED ? wb + OFF_W1 : 0, W1, b1, ZA, HA,
                                wave, lane, sbase);
    mlp_layer<32, PACKED, true>(PACKED ? wb + OFF_W2 : 0, W2, b2, HA, HA,
                                wave, lane, sbase);
    mlp_layer<32, PACKED, true>(PACKED ? wb + OFF_W3 : 0, W3, b3, HA, HA,
                                wave, lane, sbase);

    // Diagonal epilogue: ds[i] = H3[i,:] . W4[:,i] + b4[i].
    // 8 threads per row (all 512 threads active).
    int i = t >> 3, sub = t & 7;
    float p = 0.f;
#pragma unroll
    for (int q = 0; q < 8; q++) {
      int k0 = sub * 64 + q * 8;
      f16x8 hv = *(const f16x8*)&HA[aidx(i, k0)];  // j=0..7 contiguous
      if (PACKED) {
        f16x8 wv = *(const f16x8*)&wb[OFF_W4T + i * 512 + k0];
#pragma unroll
        for (int j = 0; j < 8; j++) p += (float)hv[j] * (float)wv[j];
      } else {
#pragma unroll
        for (int j = 0; j < 8; j++) p += (float)hv[j] * W4[(k0 + j) * 64 + i];
      }
    }
    p += __shfl_down(p, 4, 8);
    p += __shfl_down(p, 2, 8);
    p += __shfl_down(p, 1, 8);
    if (sub == 0) redBuf[net][i] = p + b4[i];
    __syncthreads();
  }

  if (t < 64) {
    out[b * 64 + t] = (x[b * 64 + t] - redBuf[1][t]) * __expf(-redBuf[0][t]);
  }
}

extern "C" void kernel_launch(void* const* d_in, const int* in_sizes, int n_in,
                              void* d_out, int out_size, void* d_ws, size_t ws_size,
                              hipStream_t stream) {
  const float* x    = (const float*)d_in[0];
  const float* koop = (const float*)d_in[1];
  const float* sW1 = (const float*)d_in[2];  const float* sb1 = (const float*)d_in[3];
  const float* sW2 = (const float*)d_in[4];  const float* sb2 = (const float*)d_in[5];
  const float* sW3 = (const float*)d_in[6];  const float* sb3 = (const float*)d_in[7];
  const float* sW4 = (const float*)d_in[8];  const float* sb4 = (const float*)d_in[9];
  const float* tW1 = (const float*)d_in[10]; const float* tb1 = (const float*)d_in[11];
  const float* tW2 = (const float*)d_in[12]; const float* tb2 = (const float*)d_in[13];
  const float* tW3 = (const float*)d_in[14]; const float* tb3 = (const float*)d_in[15];
  const float* tW4 = (const float*)d_in[16]; const float* tb4 = (const float*)d_in[17];
  float* out = (float*)d_out;

  // Launch-invariant branch (ws_size constant across calls) -> graph-safe.
  // NEVER write past ws_size (R1: OOB pack corrupted harness allocations).
  if (ws_size >= (size_t)WPACK_BYTES) {
    f16* wpack = (f16*)d_ws;
    pack_weights<<<576, 256, 0, stream>>>(sW1, sW2, sW3, sW4, tW1, tW2, tW3, tW4, wpack);
    decoder_main<true><<<2048, 512, 0, stream>>>(
        x, koop, wpack, sW1, sW2, sW3, sW4, tW1, tW2, tW3, tW4,
        sb1, sb2, sb3, sb4, tb1, tb2, tb3, tb4, out);
  } else {
    decoder_main<false><<<2048, 512, 0, stream>>>(
        x, koop, (const f16*)0, sW1, sW2, sW3, sW4, tW1, tW2, tW3, tW4,
        sb1, sb2, sb3, sb4, tb1, tb2, tb3, tb4, out);
  }
}